// Round 1
// baseline (661.720 us; speedup 1.0000x reference)
//
#include <hip/hip_runtime.h>

#define IN   784
#define HID  128
#define OUT  10
#define THR  0.5f

#define ROWS 64           // one wave per block; one row per thread
#define KT   16           // K-chunk width (49 chunks of 16 == 784)
#define NCHUNK (IN / KT)  // 49
#define LSTRIDE 20        // 20 floats = 80 B row pitch: 16B-aligned -> ds_*_b128,
                          // banks (20t+4k)%32 hit each bank exactly 8x/wave = b128 min

// ---------------- kernel 1: fold the network into M[10][784], c[10] ---------
__global__ void build_M(const float* __restrict__ W1, const float* __restrict__ W2,
                        const float* __restrict__ b2, float* __restrict__ M,
                        float* __restrict__ c) {
    const int i = blockIdx.x * 64 + threadIdx.x;
    if (blockIdx.x == 0 && threadIdx.x < OUT) {
        float s = b2[threadIdx.x];
        for (int h = 0; h < HID; ++h) s += W2[threadIdx.x * HID + h];
        c[threadIdx.x] = s;
    }
    if (i < IN) {
        float acc[OUT];
#pragma unroll
        for (int o = 0; o < OUT; ++o) acc[o] = 0.f;
#pragma unroll 8
        for (int h = 0; h < HID; ++h) {
            const float w = W1[h * IN + i];                 // coalesced across i
            const float t = (w > THR) ? 1.f : ((w < -THR) ? -1.f : 0.f);
#pragma unroll
            for (int o = 0; o < OUT; ++o)
                acc[o] = fmaf(W2[o * HID + h], t, acc[o]);  // W2 uniform -> s_load
        }
#pragma unroll
        for (int o = 0; o < OUT; ++o) M[o * IN + i] = acc[o];
    }
}

// ---------------- kernel 2: y = c - (x @ M^T)/784, streaming x once ---------
// 64-thread (single-wave) blocks: no inter-wave barriers (syncthreads lowers to
// a free wave-barrier), 2048 fully independent waves keep the HBM queue fed.
// Depth-2 register prefetch (A/B, statically indexed) covers ~2 chunks of
// compute per load -> ~700+ cycles of latency hiding per wave before TLP.
__global__ void __launch_bounds__(ROWS)
fused_fwd(const float* __restrict__ x, const float* __restrict__ M,
          const float* __restrict__ c, float* __restrict__ y) {
    __shared__ float xs[ROWS * LSTRIDE];                    // 5.0 KB

    const int tid  = threadIdx.x;                           // 0..63
    const int row0 = blockIdx.x * ROWS;

    // staging: 4 lanes cover one row's 16-float chunk (4 float4);
    // pass p covers rows p*16 + srow -> 16x 64B-aligned 64B segments per instr.
    const int srow = tid >> 2;                              // 0..15
    const int sc4  = tid & 3;                               // 0..3
    const float* gbase = x + (size_t)(row0 + srow) * IN + sc4 * 4;

    float4 preA[4], preB[4];
#pragma unroll
    for (int p = 0; p < 4; ++p)
        preA[p] = *reinterpret_cast<const float4*>(gbase + (size_t)(p * 16) * IN);
#pragma unroll
    for (int p = 0; p < 4; ++p)
        preB[p] = *reinterpret_cast<const float4*>(gbase + (size_t)(p * 16) * IN + KT);

    float acc[OUT];
#pragma unroll
    for (int o = 0; o < OUT; ++o) acc[o] = 0.f;

    // one chunk: drain pre -> LDS (b128), issue next loads, LDS->reg (b128), FMA
    auto body = [&](float4 (&pre)[4], const int j, const bool pf, const int jpf) {
        // regs -> LDS (compiler stages vmcnt waits on pre here); 16B-aligned
#pragma unroll
        for (int p = 0; p < 4; ++p) {
            const int b = (p * 16 + srow) * LSTRIDE + sc4 * 4;
            *reinterpret_cast<float4*>(&xs[b]) = pre[p];
        }

        // prefetch chunk jpf: max distance from its vmcnt wait (2 bodies away)
        if (pf) {
            const float* g = gbase + (size_t)jpf * KT;
#pragma unroll
            for (int p = 0; p < 4; ++p)
                pre[p] = *reinterpret_cast<const float4*>(g + (size_t)(p * 16) * IN);
        }

        __syncthreads();            // single-wave workgroup: free wave-barrier

        // thread t owns row t; 4x ds_read_b128, conflict-free with pitch 20
        float4 xv[4];
#pragma unroll
        for (int k4 = 0; k4 < 4; ++k4)
            xv[k4] = *reinterpret_cast<const float4*>(&xs[tid * LSTRIDE + k4 * 4]);

        const int k0 = j * KT;
#pragma unroll
        for (int k4 = 0; k4 < 4; ++k4) {
            const float4 xq = xv[k4];
#pragma unroll
            for (int o = 0; o < OUT; ++o) {
                // uniform address -> s_load_dwordx4; SGPR operand in v_fmac
                const float4 m =
                    *reinterpret_cast<const float4*>(M + o * IN + k0 + k4 * 4);
                acc[o] = fmaf(xq.x, m.x, acc[o]);
                acc[o] = fmaf(xq.y, m.y, acc[o]);
                acc[o] = fmaf(xq.z, m.z, acc[o]);
                acc[o] = fmaf(xq.w, m.w, acc[o]);
            }
        }
        __syncthreads();            // order xs reuse before next body's writes
    };

#pragma unroll 1
    for (int j = 0; j < NCHUNK - 1; j += 2) {       // j = 0,2,...,46
        body(preA, j,     true,            j + 2);  // j+2 <= 48 always in-bounds
        body(preB, j + 1, j + 3 < NCHUNK,  j + 3);  // skip OOB chunk 49 at j=46
    }
    body(preA, NCHUNK - 1, false, 0);               // chunk 48, no prefetch

    const float inv = 1.0f / (float)IN;
#pragma unroll
    for (int o = 0; o < OUT; ++o)
        y[(size_t)(row0 + tid) * OUT + o] = c[o] - acc[o] * inv;
}

extern "C" void kernel_launch(void* const* d_in, const int* in_sizes, int n_in,
                              void* d_out, int out_size, void* d_ws, size_t ws_size,
                              hipStream_t stream) {
    const float* x  = (const float*)d_in[0];
    const float* W1 = (const float*)d_in[1];
    const float* W2 = (const float*)d_in[2];
    const float* b2 = (const float*)d_in[3];
    float* y = (float*)d_out;

    float* M = (float*)d_ws;        // OUT*IN floats = 31.4 KB scratch
    float* c = M + OUT * IN;        // OUT floats

    const int B = in_sizes[0] / IN; // 131072

    build_M<<<(IN + 63) / 64, 64, 0, stream>>>(W1, W2, b2, M, c);
    fused_fwd<<<B / ROWS, ROWS, 0, stream>>>(x, M, c, y);
}

// Round 2
// 634.886 us; speedup vs baseline: 1.0423x; 1.0423x over previous
//
#include <hip/hip_runtime.h>

#define IN   784
#define HID  128
#define OUT  10
#define THR  0.5f

#define TPB  256          // threads per block (4 waves) — proven r0 shape
#define RPB  128          // rows per block; thread lt owns row lt in its K-half
#define KT   16           // K-chunk width
#define NCHUNK 49         // 784/16
#define SPLIT  25         // half 0: chunks [0,25)=k<400; half 1: [25,49)=k 400..783
#define LSTRIDE (KT + 1)  // pad -> read banks (17*t+k)%32: 2-way, free (r0-proven)

// ---------------- kernel 1: fold the network into M[10][784], c[10] ---------
__global__ void build_M(const float* __restrict__ W1, const float* __restrict__ W2,
                        const float* __restrict__ b2, float* __restrict__ M,
                        float* __restrict__ c) {
    const int i = blockIdx.x * 64 + threadIdx.x;
    if (blockIdx.x == 0 && threadIdx.x < OUT) {
        float s = b2[threadIdx.x];
        for (int h = 0; h < HID; ++h) s += W2[threadIdx.x * HID + h];
        c[threadIdx.x] = s;
    }
    if (i < IN) {
        float acc[OUT];
#pragma unroll
        for (int o = 0; o < OUT; ++o) acc[o] = 0.f;
#pragma unroll 8
        for (int h = 0; h < HID; ++h) {
            const float w = W1[h * IN + i];                 // coalesced across i
            const float t = (w > THR) ? 1.f : ((w < -THR) ? -1.f : 0.f);
#pragma unroll
            for (int o = 0; o < OUT; ++o)
                acc[o] = fmaf(W2[o * HID + h], t, acc[o]);  // W2 uniform -> s_load
        }
#pragma unroll
        for (int o = 0; o < OUT; ++o) M[o * IN + i] = acc[o];
    }
}

// ---------------- kernel 2: y = c - (x @ M^T)/784, streaming x once ---------
// r0 structure with ONE change: 2-way K-split across the block's wave-pairs.
// Waves 0-1 (half 0) compute chunks [0,25) for rows 0..127; waves 2-3 (half 1)
// compute chunks [25,49) for the same rows, each staging into its own LDS
// region. Grid doubles to 1024 blocks -> 4096 waves = 16/CU (4/SIMD), doubling
// the TLP that covers the ~900-cycle HBM latency per chunk. Per-wave load
// pattern, LDS banking, prefetch depth, and scalar M path identical to r0.
__global__ void __launch_bounds__(TPB)
fused_fwd(const float* __restrict__ x, const float* __restrict__ M,
          const float* __restrict__ c, float* __restrict__ y) {
    __shared__ float xs[2 * RPB * LSTRIDE];                 // 17.4 KB

    const int tid  = threadIdx.x;                           // 0..255
    const int half = tid >> 7;                              // 0,1 (wave-pair)
    const int lt   = tid & 127;                             // owns row lt
    const int row0 = blockIdx.x * RPB;

    const int jlo = half ? SPLIT : 0;                       // wave-uniform
    const int jhi = half ? NCHUNK : SPLIT;
    float* xh = xs + half * (RPB * LSTRIDE);

    // staging mapping (per half): 4 lanes cover one row's 16-float chunk;
    // pass p covers rows p*32 + srow -> 16x 64B segments per wave-instr.
    const int srow = lt >> 2;                               // 0..31
    const int sc4  = lt & 3;                                // 0..3
    const float* gbase = x + (size_t)(row0 + srow) * IN + sc4 * 4;

    float4 pre[4];
#pragma unroll
    for (int p = 0; p < 4; ++p)
        pre[p] = *reinterpret_cast<const float4*>(
            gbase + (size_t)(p * 32) * IN + jlo * KT);

    float acc[OUT];
#pragma unroll
    for (int o = 0; o < OUT; ++o) acc[o] = 0.f;

#pragma unroll 1
    for (int i = 0; i < SPLIT; ++i) {                       // 25 iters, uniform
        const int j   = jlo + i;
        const bool act = (j < jhi);     // half0: always; half1: idle last iter

        if (act) {                      // regs -> LDS (vmcnt wait lands here)
#pragma unroll
            for (int p = 0; p < 4; ++p) {
                const int b = (p * 32 + srow) * LSTRIDE + sc4 * 4;
                xh[b + 0] = pre[p].x;
                xh[b + 1] = pre[p].y;
                xh[b + 2] = pre[p].z;
                xh[b + 3] = pre[p].w;
            }
        }
        __syncthreads();

        // prefetch next chunk: loads in flight under the compute phase
        if (j + 1 < jhi) {
            const float* g = gbase + (size_t)(j + 1) * KT;
#pragma unroll
            for (int p = 0; p < 4; ++p)
                pre[p] = *reinterpret_cast<const float4*>(
                    g + (size_t)(p * 32) * IN);
        }

        if (act) {
            // thread lt owns row lt; banks (17*lt+k)%32 -> 2-way, free
            float xv[KT];
#pragma unroll
            for (int k = 0; k < KT; ++k) xv[k] = xh[lt * LSTRIDE + k];

            const int k0 = j * KT;
#pragma unroll
            for (int k4 = 0; k4 < KT / 4; ++k4) {
#pragma unroll
                for (int o = 0; o < OUT; ++o) {
                    // uniform address (j wave-uniform) -> s_load_dwordx4
                    const float4 m = *reinterpret_cast<const float4*>(
                        M + o * IN + k0 + k4 * 4);
                    acc[o] = fmaf(xv[k4 * 4 + 0], m.x, acc[o]);
                    acc[o] = fmaf(xv[k4 * 4 + 1], m.y, acc[o]);
                    acc[o] = fmaf(xv[k4 * 4 + 2], m.z, acc[o]);
                    acc[o] = fmaf(xv[k4 * 4 + 3], m.w, acc[o]);
                }
            }
        }
        __syncthreads();
    }

    // combine the two K-halves through LDS (xs region free after last barrier)
    if (half) {
#pragma unroll
        for (int o = 0; o < OUT; ++o) xs[lt * OUT + o] = acc[o];
    }
    __syncthreads();
    if (!half) {
        const float inv = 1.0f / (float)IN;
#pragma unroll
        for (int o = 0; o < OUT; ++o) {
            const float s = acc[o] + xs[lt * OUT + o];
            y[(size_t)(row0 + lt) * OUT + o] = c[o] - s * inv;
        }
    }
}

extern "C" void kernel_launch(void* const* d_in, const int* in_sizes, int n_in,
                              void* d_out, int out_size, void* d_ws, size_t ws_size,
                              hipStream_t stream) {
    const float* x  = (const float*)d_in[0];
    const float* W1 = (const float*)d_in[1];
    const float* W2 = (const float*)d_in[2];
    const float* b2 = (const float*)d_in[3];
    float* y = (float*)d_out;

    float* M = (float*)d_ws;        // OUT*IN floats = 31.4 KB scratch
    float* c = M + OUT * IN;        // OUT floats

    const int B = in_sizes[0] / IN; // 131072

    build_M<<<(IN + 63) / 64, 64, 0, stream>>>(W1, W2, b2, M, c);
    fused_fwd<<<B / RPB, TPB, 0, stream>>>(x, M, c, y);
}

// Round 3
// 562.149 us; speedup vs baseline: 1.1771x; 1.1294x over previous
//
#include <hip/hip_runtime.h>

#define IN   784
#define HID  128
#define OUT  10
#define THR  0.5f

#define TPB  256          // 4 waves per block, 2 blocks/CU — proven r0 shape
#define KT   16           // K-chunk width
#define NCHUNK 49         // 784/16
#define WROWS 64          // rows per wave; thread = row, wave-private tile
#define LSTRIDE (KT + 1)  // pad -> banks (17*t+k)%32: exactly 2-way, free (r0-proven)

// ---------------- kernel 1: fold the network into M[10][784], c[10] ---------
__global__ void build_M(const float* __restrict__ W1, const float* __restrict__ W2,
                        const float* __restrict__ b2, float* __restrict__ M,
                        float* __restrict__ c) {
    const int i = blockIdx.x * 64 + threadIdx.x;
    if (blockIdx.x == 0 && threadIdx.x < OUT) {
        float s = b2[threadIdx.x];
        for (int h = 0; h < HID; ++h) s += W2[threadIdx.x * HID + h];
        c[threadIdx.x] = s;
    }
    if (i < IN) {
        float acc[OUT];
#pragma unroll
        for (int o = 0; o < OUT; ++o) acc[o] = 0.f;
#pragma unroll 8
        for (int h = 0; h < HID; ++h) {
            const float w = W1[h * IN + i];                 // coalesced across i
            const float t = (w > THR) ? 1.f : ((w < -THR) ? -1.f : 0.f);
#pragma unroll
            for (int o = 0; o < OUT; ++o)
                acc[o] = fmaf(W2[o * HID + h], t, acc[o]);  // W2 uniform -> s_load
        }
#pragma unroll
        for (int o = 0; o < OUT; ++o) M[o * IN + i] = acc[o];
    }
}

// ---------------- kernel 2: y = c - (x @ M^T)/784, streaming x once ---------
// r0 structure with ONE change: the LDS tile is WAVE-PRIVATE, so there are no
// __syncthreads() at all. r0's two barriers per chunk each forced a
// s_waitcnt vmcnt(0) drain of the prefetch loads and lockstepped all 4 waves;
// here each wave stages and consumes only its own 64 rows, ordering is via
// wave-local lgkmcnt waits, and the block's waves free-run against each other.
// Per-wave global pattern (16x 64B segments/instr), LDS banking (LSTRIDE 17),
// prefetch depth, and the scalar-M FMA loop are byte-identical to r0.
__global__ void __launch_bounds__(TPB)
fused_fwd(const float* __restrict__ x, const float* __restrict__ M,
          const float* __restrict__ c, float* __restrict__ y) {
    __shared__ float xs[TPB / 64][WROWS * LSTRIDE];         // 17.4 KB total

    const int lane = threadIdx.x & 63;
    const int wave = threadIdx.x >> 6;
    const int rowbase = blockIdx.x * TPB + wave * WROWS;    // wave owns 64 rows

    // staging mapping (per wave): 4 lanes cover one row's 16-float chunk;
    // pass p covers rows p*16 + srow -> 16x 64B-aligned segments per instr.
    const int srow = lane >> 2;                             // 0..15
    const int sc4  = lane & 3;                              // 0..3
    const float* gbase = x + (size_t)(rowbase + srow) * IN + sc4 * 4;
    float* xw = xs[wave];                                   // private region

    float4 pre[4];
#pragma unroll
    for (int p = 0; p < 4; ++p)
        pre[p] = *reinterpret_cast<const float4*>(gbase + (size_t)(p * 16) * IN);

    float acc[OUT];
#pragma unroll
    for (int o = 0; o < OUT; ++o) acc[o] = 0.f;

#pragma unroll 1
    for (int j = 0; j < NCHUNK; ++j) {
        // regs -> LDS (compiler waits vmcnt on pre here; wave-local only)
#pragma unroll
        for (int p = 0; p < 4; ++p) {
            const int b = (p * 16 + srow) * LSTRIDE + sc4 * 4;
            xw[b + 0] = pre[p].x;
            xw[b + 1] = pre[p].y;
            xw[b + 2] = pre[p].z;
            xw[b + 3] = pre[p].w;
        }
        __builtin_amdgcn_wave_barrier();    // compile-time order pin, 0 cost

        // prefetch next chunk: loads in flight under the compute phase
        if (j + 1 < NCHUNK) {
            const float* g = gbase + (size_t)(j + 1) * KT;
#pragma unroll
            for (int p = 0; p < 4; ++p)
                pre[p] = *reinterpret_cast<const float4*>(
                    g + (size_t)(p * 16) * IN);
        }

        // thread owns row `lane`: banks (17*lane+k)%32 -> 2-way, free
        float xv[KT];
#pragma unroll
        for (int k = 0; k < KT; ++k) xv[k] = xw[lane * LSTRIDE + k];
        __builtin_amdgcn_wave_barrier();    // reads before next iter's writes

        const int k0 = j * KT;
#pragma unroll
        for (int k4 = 0; k4 < KT / 4; ++k4) {
#pragma unroll
            for (int o = 0; o < OUT; ++o) {
                // uniform address (j wave-uniform) -> s_load_dwordx4
                const float4 m =
                    *reinterpret_cast<const float4*>(M + o * IN + k0 + k4 * 4);
                acc[o] = fmaf(xv[k4 * 4 + 0], m.x, acc[o]);
                acc[o] = fmaf(xv[k4 * 4 + 1], m.y, acc[o]);
                acc[o] = fmaf(xv[k4 * 4 + 2], m.z, acc[o]);
                acc[o] = fmaf(xv[k4 * 4 + 3], m.w, acc[o]);
            }
        }
    }

    const float inv = 1.0f / (float)IN;
#pragma unroll
    for (int o = 0; o < OUT; ++o)
        y[(size_t)(rowbase + lane) * OUT + o] = c[o] - acc[o] * inv;
}

extern "C" void kernel_launch(void* const* d_in, const int* in_sizes, int n_in,
                              void* d_out, int out_size, void* d_ws, size_t ws_size,
                              hipStream_t stream) {
    const float* x  = (const float*)d_in[0];
    const float* W1 = (const float*)d_in[1];
    const float* W2 = (const float*)d_in[2];
    const float* b2 = (const float*)d_in[3];
    float* y = (float*)d_out;

    float* M = (float*)d_ws;        // OUT*IN floats = 31.4 KB scratch
    float* c = M + OUT * IN;        // OUT floats

    const int B = in_sizes[0] / IN; // 131072

    build_M<<<(IN + 63) / 64, 64, 0, stream>>>(W1, W2, b2, M, c);
    fused_fwd<<<B / TPB, TPB, 0, stream>>>(x, M, c, y);
}